// Round 16
// baseline (226.903 us; speedup 1.0000x reference)
//
#include <hip/hip_runtime.h>
#include <hip/hip_bf16.h>
#include <stdint.h>

#define S_LEN 2048
#define HD 4096            // H*D row stride in floats
#define QB 64
#define KB 32

#define LAMBDA_INIT_F 0.78360576654f
#define ONE_MINUS_LI  0.21639423346f
#define SCALE_F 0.08838834764831845f  // 1/sqrt(128)
#define CMAX_F 16.0f                   // static softmax shift: P = exp(s - 16)

typedef __attribute__((ext_vector_type(8))) short bf16x8;
typedef __attribute__((ext_vector_type(4))) float f32x4;
typedef __attribute__((ext_vector_type(4))) uint32_t u32x4;
typedef __attribute__((ext_vector_type(2))) uint32_t u32x2;

// Loop LDS (bytes): Kb[2] @0,@16384; Vb[2] @32768,@49152; P[2] @65536 (2x8KB, dbuf).
// Epilogue overlay: X2[64][260] f32 @0 (66560), Ssum[2][64] @66560, LR @67072.
// SM_BYTES=81920 -> exactly 2 blocks/CU (163840 = 160KB).
#define SMB_VBASE 32768u
#define SMB_P 65536u
#define SMB_SS 66560u
#define SMB_LR 67072u
#define SM_BYTES 81920

// ws blob: per (b,hp,kt) 32 KB = [K image 16KB][V image 16KB], byte-exact LDS content
#define BLOB_BYTES 32768u

__device__ __forceinline__ unsigned short f2bf(float x) {
  union { __hip_bfloat16 h; unsigned short u; } v;
  v.h = __float2bfloat16(x);
  return v.u;
}
__device__ __forceinline__ uint32_t pk2(float a, float b) {
  return (uint32_t)f2bf(a) | ((uint32_t)f2bf(b) << 16);
}
// K image (within 16KB buffer): [att*32+row][128 d] bf16, 256B rows, XOR-swizzled
__device__ __forceinline__ uint32_t kb_byte(int att, int row, int d) {
  uint32_t o = ((uint32_t)(att * 32 + row)) * 256u + ((uint32_t)d) * 2u;
  return o ^ (((uint32_t)(row & 7)) << 4);
}
// V image (within 16KB buffer)
__device__ __forceinline__ uint32_t v_base(int col, int k) {
  uint32_t o = ((uint32_t)(col >> 2)) * 256u + ((uint32_t)(k >> 3)) * 64u +
               ((uint32_t)(col & 3)) * 16u + ((uint32_t)(k & 7)) * 2u;
  o ^= (((uint32_t)((col >> 2) & 7)) << 4);
  o ^= (((uint32_t)((col >> 2) & 1)) << 6);
  return o;
}
// P (within 8KB buffer): [att][q 0..63][k 0..31] bf16, 64B rows,
// XOR-swizzled byte ^= (qrow&6)<<3
__device__ __forceinline__ uint32_t p_off(int att, int qrow, int k) {
  uint32_t o = (((uint32_t)(att * 64 + qrow)) * 32u + (uint32_t)k) * 2u;
  return SMB_P + (o ^ (((uint32_t)(qrow & 6)) << 3));
}

// ---------------- pre-pass: pack K/V into bf16 LDS-image blobs ----------------
__global__ __launch_bounds__(256, 4)
void pack_kv(const float* __restrict__ Kg, const float* __restrict__ Vg,
             char* __restrict__ ws) {
  __shared__ float lv[32 * 264];
  const int n = blockIdx.x;          // (b*16+hp)*64 + kt
  const int kt = n & 63;
  const int bh = n >> 6;
  const int b = bh >> 4;
  const int hp = bh & 15;
  const int t = threadIdx.x;
  char* blob = ws + (size_t)n * BLOB_BYTES;

  // ---- K image ----
  {
    const int r64 = t >> 2;
    const int att = r64 >> 5, row = r64 & 31;
    const int dq = (t & 3) * 32;
    const float* src =
        Kg + (size_t)(b * S_LEN + kt * KB + row) * HD + (2 * hp + att) * 128 + dq;
    float e[32];
    #pragma unroll
    for (int m = 0; m < 8; ++m) {
      f32x4 f = *(const f32x4*)(src + 4 * m);
      e[4 * m + 0] = f[0]; e[4 * m + 1] = f[1];
      e[4 * m + 2] = f[2]; e[4 * m + 3] = f[3];
    }
    #pragma unroll
    for (int m = 0; m < 4; ++m) {
      u32x4 w;
      w.x = pk2(e[8 * m + 0], e[8 * m + 1]);
      w.y = pk2(e[8 * m + 2], e[8 * m + 3]);
      w.z = pk2(e[8 * m + 4], e[8 * m + 5]);
      w.w = pk2(e[8 * m + 6], e[8 * m + 7]);
      *(u32x4*)(blob + kb_byte(att, row, dq + 8 * m)) = w;
    }
  }
  // ---- V -> LDS f32 ----
  {
    const int r = t >> 3, s = (t & 7) * 32;
    const float* src = Vg + (size_t)(b * S_LEN + kt * KB + r) * HD + hp * 256 + s;
    #pragma unroll
    for (int m = 0; m < 8; ++m)
      *(f32x4*)(lv + r * 264 + s + 4 * m) = *(const f32x4*)(src + 4 * m);
  }
  __syncthreads();
  // ---- V image ----
  {
    const int col = t;
    #pragma unroll
    for (int k8 = 0; k8 < 4; ++k8) {
      float v0 = lv[(8 * k8 + 0) * 264 + col];
      float v1 = lv[(8 * k8 + 1) * 264 + col];
      float v2 = lv[(8 * k8 + 2) * 264 + col];
      float v3 = lv[(8 * k8 + 3) * 264 + col];
      float v4 = lv[(8 * k8 + 4) * 264 + col];
      float v5 = lv[(8 * k8 + 5) * 264 + col];
      float v6 = lv[(8 * k8 + 6) * 264 + col];
      float v7 = lv[(8 * k8 + 7) * 264 + col];
      u32x4 w;
      w.x = pk2(v0, v1); w.y = pk2(v2, v3);
      w.z = pk2(v4, v5); w.w = pk2(v6, v7);
      *(u32x4*)(blob + 16384 + v_base(col, 8 * k8)) = w;
    }
  }
}

// --- attention: QB=64, ki-split, dbuf K/V/P, unroll-2 (static parities), 1 barrier ---
__global__ __launch_bounds__(512, 2)
void diffattn_fwd(const float* __restrict__ Qg, const char* __restrict__ ws,
                  const float* __restrict__ lq1, const float* __restrict__ lk1,
                  const float* __restrict__ lq2, const float* __restrict__ lk2,
                  const float* __restrict__ Wg, float* __restrict__ Og) {
  __shared__ __align__(16) char sm[SM_BYTES];

  const int tid = threadIdx.x;
  const int lane = tid & 63;
  const int c = lane & 15;       // MFMA lane col index (= q-row within 16-subtile)
  const int g = lane >> 4;       // MFMA k-group
  const int wv = tid >> 6;       // 0..7
  const int att = wv >> 2;       // which attention (q1k1 / q2k2)
  const int qh = (wv >> 1) & 1;  // which 32-row half of the 64-row q block
  const int ch = wv & 1;         // V column half AND k-row half (ki) for QK

  // block swizzle: 4 (b,hp) per XCD, qt descending (heavy blocks first)
  const int n = blockIdx.x;               // 0..1023
  const int bh = (n & 7) * 4 + ((n >> 3) >> 5);
  const int qt = 31 - ((n >> 3) & 31);
  const int b = bh >> 4;
  const int hp = bh & 15;
  const int qb = qt * QB;
  const int nt = 2 * qt + 2;              // k-tiles (KB=32), ALWAYS EVEN, >= 2

  const float* qg = Qg + (size_t)b * S_LEN * HD + (size_t)hp * 256 + (size_t)qb * HD;
  const char* bhb = ws + (size_t)(b * 16 + hp) * (64u * BLOB_BYTES);

  // lambda (per-wave shuffle reduce)
  float d1 = lq1[lane] * lk1[lane] + lq1[lane + 64] * lk1[lane + 64];
  float d2 = lq2[lane] * lk2[lane] + lq2[lane + 64] * lk2[lane + 64];
  #pragma unroll
  for (int m = 1; m < 64; m <<= 1) {
    d1 += __shfl_xor(d1, m, 64);
    d2 += __shfl_xor(d2, m, 64);
  }
  const float lam = __expf(d1) - __expf(d2) + LAMBDA_INIT_F;

  // ---- Q fragments direct from global (SCALE folded) ----
  bf16x8 qf[2][4];
  #pragma unroll
  for (int qi = 0; qi < 2; ++qi) {
    const float* qrow_p = qg + (size_t)(qh * 32 + qi * 16 + c) * HD + att * 128;
    #pragma unroll
    for (int kk = 0; kk < 4; ++kk) {
      f32x4 lo = *(const f32x4*)(qrow_p + 32 * kk + 8 * g);
      f32x4 hi = *(const f32x4*)(qrow_p + 32 * kk + 8 * g + 4);
      union { bf16x8 h; u32x4 u; } r;
      r.u.x = pk2(lo[0] * SCALE_F, lo[1] * SCALE_F);
      r.u.y = pk2(lo[2] * SCALE_F, lo[3] * SCALE_F);
      r.u.z = pk2(hi[0] * SCALE_F, hi[1] * SCALE_F);
      r.u.w = pk2(hi[2] * SCALE_F, hi[3] * SCALE_F);
      qf[qi][kk] = r.h;
    }
  }

  // ---- per-lane-constant LDS byte offsets (buffer-relative) ----
  uint32_t kfo[4], vbo[8];
  #pragma unroll
  for (int kk = 0; kk < 4; ++kk) kfo[kk] = kb_byte(att, 16 * ch + c, 32 * kk + 8 * g);
  #pragma unroll
  for (int cf = 0; cf < 8; ++cf) vbo[cf] = v_base(128 * ch + 16 * cf + c, 8 * g);
  const uint32_t pa0_off = p_off(att, qh * 32 + c, 8 * g);
  const uint32_t pa1_off = p_off(att, qh * 32 + 16 + c, 8 * g);
  const uint32_t pw0_off = p_off(att, qh * 32 + c, 16 * ch + 4 * g);
  const uint32_t pw1_off = p_off(att, qh * 32 + 16 + c, 16 * ch + 4 * g);
  const int lr_self = (((att * 2 + qh) * 2 + ch) << 5);
  const int lr_twin = (((att * 2 + qh) * 2 + (ch ^ 1)) << 5);

  // ---- blob staging regs ----
  u32x4 ks0, ks1, vs0, vs1;
  const uint32_t woff = 2048u * wv + 16u * lane;
  auto ISSUE_K = [&](int i) {
    const char* s0 = bhb + (size_t)i * BLOB_BYTES + woff;
    ks0 = *(const u32x4*)(s0);
    ks1 = *(const u32x4*)(s0 + 1024);
  };
  auto ISSUE_V = [&](int i) {
    const char* s0 = bhb + (size_t)i * BLOB_BYTES + 16384u + woff;
    vs0 = *(const u32x4*)(s0);
    vs1 = *(const u32x4*)(s0 + 1024);
  };

  f32x4 o[2][8];
  #pragma unroll
  for (int qi = 0; qi < 2; ++qi)
    #pragma unroll
    for (int cf = 0; cf < 8; ++cf) o[qi][cf] = (f32x4){0.f, 0.f, 0.f, 0.f};
  float lrow[2] = {0.f, 0.f};   // per-lane partial sums (own k slots); reduced in epilogue

  f32x4 stA, stB;               // S^T for the tile whose softmax is pending

  // QK for tile i reading K buffer parity kpar (compile-time where possible)
  auto QK = [&](int i, uint32_t kbase) {
    stA = (f32x4){0.f, 0.f, 0.f, 0.f};
    stB = (f32x4){0.f, 0.f, 0.f, 0.f};
    #pragma unroll
    for (int kk = 0; kk < 4; ++kk) {
      bf16x8 kf = *(const bf16x8*)(sm + kbase + kfo[kk]);
      stA = __builtin_amdgcn_mfma_f32_16x16x32_bf16(kf, qf[0][kk], stA, 0, 0, 0);
      stB = __builtin_amdgcn_mfma_f32_16x16x32_bf16(kf, qf[1][kk], stB, 0, 0, 0);
    }
    if (i >= 2 * qt) {
      const int koff = (i - 2 * qt) * 32 + 16 * ch;
      #pragma unroll
      for (int r = 0; r < 4; ++r) {
        if (koff + 4 * g + r > qh * 32 + c) stA[r] = -1e30f;
        if (koff + 4 * g + r > qh * 32 + 16 + c) stB[r] = -1e30f;
      }
    }
  };

  // static-max softmax: P = exp(s - 16); write into P buffer at byte offset pb
  auto SM_P = [&](uint32_t pb) {
    {
      float p0 = __expf(stA[0] - CMAX_F);
      float p1 = __expf(stA[1] - CMAX_F);
      float p2 = __expf(stA[2] - CMAX_F);
      float p3 = __expf(stA[3] - CMAX_F);
      lrow[0] += (p0 + p1) + (p2 + p3);
      u32x2 w;
      w.x = pk2(p0, p1); w.y = pk2(p2, p3);
      *(u32x2*)(sm + pw0_off + pb) = w;
    }
    {
      float p0 = __expf(stB[0] - CMAX_F);
      float p1 = __expf(stB[1] - CMAX_F);
      float p2 = __expf(stB[2] - CMAX_F);
      float p3 = __expf(stB[3] - CMAX_F);
      lrow[1] += (p0 + p1) + (p2 + p3);
      u32x2 w;
      w.x = pk2(p0, p1); w.y = pk2(p2, p3);
      *(u32x2*)(sm + pw1_off + pb) = w;
    }
  };

  // one loop iteration with compile-time parity PAR (tt = t has parity PAR)
  #define ITER(tt, PAR)                                                          \
    {                                                                            \
      /* hoisted pa reads: P[PAR] ready since before previous barrier */         \
      bf16x8 pa0 = *(const bf16x8*)(sm + pa0_off + ((PAR) ? 8192u : 0u));        \
      bf16x8 pa1 = *(const bf16x8*)(sm + pa1_off + ((PAR) ? 8192u : 0u));        \
      /* staging writes for future tiles (buffers free since last barrier) */    \
      if ((tt) + 2 < nt) {                                                       \
        char* d = sm + ((PAR) ? 16384u : 0u) + woff;                             \
        *(u32x4*)(d) = ks0;                                                      \
        *(u32x4*)(d + 1024) = ks1;                                               \
      }                                                                          \
      if ((tt) + 1 < nt) {                                                       \
        char* d = sm + SMB_VBASE + ((PAR) ? 0u : 16384u) + woff;                 \
        *(u32x4*)(d) = vs0;                                                      \
        *(u32x4*)(d + 1024) = vs1;                                               \
      }                                                                          \
      if ((tt) + 3 < nt) ISSUE_K((tt) + 3);                                      \
      if ((tt) + 2 < nt) ISSUE_V((tt) + 2);                                      \
      const bool more = (tt) + 1 < nt;                                           \
      __builtin_amdgcn_s_setprio(1);                                             \
      if (more) QK((tt) + 1, (PAR) ? 0u : 16384u);                               \
      _Pragma("unroll")                                                          \
      for (int cf = 0; cf < 8; ++cf) {                                           \
        bf16x8 vf = *(const bf16x8*)(sm + SMB_VBASE + ((PAR) ? 16384u : 0u) +    \
                                     vbo[cf]);                                   \
        o[0][cf] = __builtin_amdgcn_mfma_f32_16x16x32_bf16(pa0, vf, o[0][cf],    \
                                                           0, 0, 0);             \
        o[1][cf] = __builtin_amdgcn_mfma_f32_16x16x32_bf16(pa1, vf, o[1][cf],    \
                                                           0, 0, 0);             \
      }                                                                          \
      __builtin_amdgcn_s_setprio(0);                                             \
      if (more) {                                                                \
        SM_P((PAR) ? 0u : 8192u);                                                \
        __syncthreads();                                                         \
      }                                                                          \
    }

  // ---- prologue ----
  ISSUE_K(0); ISSUE_V(0);
  {
    char* d = sm + woff;                 // Kbuf[0]
    *(u32x4*)(d) = ks0; *(u32x4*)(d + 1024) = ks1;
    char* e = sm + SMB_VBASE + woff;     // Vbuf[0]
    *(u32x4*)(e) = vs0; *(u32x4*)(e + 1024) = vs1;
  }
  ISSUE_K(1);
  __syncthreads();                  // K(0), V(0) visible
  QK(0, 0u);                        // reads Kbuf[0]
  {
    char* d = sm + 16384u + woff;   // ks=K(1) -> Kbuf[1]
    *(u32x4*)(d) = ks0; *(u32x4*)(d + 1024) = ks1;
  }
  if (2 < nt) ISSUE_K(2);           // for WRITE_K(2) at top of t=0
  ISSUE_V(1);                       // for WRITE_V(1) at top of t=0
  SM_P(0u);                         // softmax(0) -> P[0]
  __syncthreads();                  // delta(-1): Kbuf[1], P[0] visible

  // ---- main loop, unrolled x2 (nt always even; t even => both halves run) ----
  for (int t = 0; t < nt; t += 2) {
    ITER(t, 0);
    ITER(t + 1, 1);
  }
  #undef ITER

  // ---- epilogue: reduce lrow over g, merge twin halves, fp32 combine + RMSNorm ----
  float lred[2];
  #pragma unroll
  for (int qi = 0; qi < 2; ++qi) {
    float lr = lrow[qi];
    lr += __shfl_xor(lr, 16, 64);
    lr += __shfl_xor(lr, 32, 64);
    lred[qi] = lr;
  }
  __syncthreads();                  // all waves done with loop LDS before overlay
  float* LRf = (float*)(sm + SMB_LR);
  if (g == 0) {
    LRf[lr_self + c] = lred[0];
    LRf[lr_self + 16 + c] = lred[1];
  }
  __syncthreads();
  float lv[2][4];
  #pragma unroll
  for (int qi = 0; qi < 2; ++qi) {
    float lt = lred[qi] + LRf[lr_twin + qi * 16 + c];
    float li = 1.f / lt;
    #pragma unroll
    for (int r = 0; r < 4; ++r) lv[qi][r] = __shfl(li, 4 * g + r, 64);
  }
  float* X2 = (float*)sm;                  // [64][260] f32 overlay
  float* Ssum = (float*)(sm + SMB_SS);     // [2][64] f32

  if (att == 1) {
    #pragma unroll
    for (int qi = 0; qi < 2; ++qi)
      #pragma unroll
      for (int cf = 0; cf < 8; ++cf)
        #pragma unroll
        for (int r = 0; r < 4; ++r)
          X2[(qh * 32 + qi * 16 + 4 * g + r) * 260 + 128 * ch + 16 * cf + c] =
              o[qi][cf][r] * lv[qi][r];
  }
  __syncthreads();
  if (att == 0) {
    float ss[2][4] = {{0.f, 0.f, 0.f, 0.f}, {0.f, 0.f, 0.f, 0.f}};
    #pragma unroll
    for (int qi = 0; qi < 2; ++qi)
      #pragma unroll
      for (int cf = 0; cf < 8; ++cf)
        #pragma unroll
        for (int r = 0; r < 4; ++r) {
          float xx = o[qi][cf][r] * lv[qi][r] -
                     lam * X2[(qh * 32 + qi * 16 + 4 * g + r) * 260 +
                              128 * ch + 16 * cf + c];
          o[qi][cf][r] = xx;
          ss[qi][r] += xx * xx;
        }
    #pragma unroll
    for (int m = 1; m < 16; m <<= 1)
      #pragma unroll
      for (int qi = 0; qi < 2; ++qi)
        #pragma unroll
        for (int r = 0; r < 4; ++r) ss[qi][r] += __shfl_xor(ss[qi][r], m, 64);
    if (c == 0) {
      #pragma unroll
      for (int qi = 0; qi < 2; ++qi)
        #pragma unroll
        for (int r = 0; r < 4; ++r)
          Ssum[ch * 64 + qh * 32 + qi * 16 + 4 * g + r] = ss[qi][r];
    }
  }
  __syncthreads();
  if (att == 0) {
    float rsv[2][4];
    #pragma unroll
    for (int qi = 0; qi < 2; ++qi)
      #pragma unroll
      for (int r = 0; r < 4; ++r) {
        int row = qh * 32 + qi * 16 + 4 * g + r;
        float s = Ssum[row] + Ssum[64 + row];
        rsv[qi][r] = rsqrtf(s * (1.f / 256.f) + 1e-5f) * ONE_MINUS_LI;
      }
    #pragma unroll
    for (int cf = 0; cf < 8; ++cf) {
      float w = Wg[128 * ch + 16 * cf + c];
      #pragma unroll
      for (int qi = 0; qi < 2; ++qi)
        #pragma unroll
        for (int r = 0; r < 4; ++r) {
          int row = qh * 32 + qi * 16 + 4 * g + r;
          Og[(size_t)((size_t)b * S_LEN + qb + row) * HD + hp * 256 +
             128 * ch + 16 * cf + c] = w * o[qi][cf][r] * rsv[qi][r];
        }
    }
  }
}

extern "C" void kernel_launch(void* const* d_in, const int* in_sizes, int n_in,
                              void* d_out, int out_size, void* d_ws, size_t ws_size,
                              hipStream_t stream) {
  const float* q   = (const float*)d_in[0];
  const float* k   = (const float*)d_in[1];
  const float* v   = (const float*)d_in[2];
  const float* lq1 = (const float*)d_in[3];
  const float* lk1 = (const float*)d_in[4];
  const float* lq2 = (const float*)d_in[5];
  const float* lk2 = (const float*)d_in[6];
  const float* w   = (const float*)d_in[7];
  float* out = (float*)d_out;
  char* ws = (char*)d_ws;
  hipLaunchKernelGGL(pack_kv, dim3(2048), dim3(256), 0, stream, k, v, ws);
  hipLaunchKernelGGL(diffattn_fwd, dim3(1024), dim3(512), 0, stream,
                     q, ws, lq1, lk1, lq2, lk2, w, out);
}

// Round 17
// 215.468 us; speedup vs baseline: 1.0531x; 1.0531x over previous
//
#include <hip/hip_runtime.h>
#include <hip/hip_bf16.h>
#include <stdint.h>

#define S_LEN 2048
#define HD 4096            // H*D row stride in floats
#define QB 64
#define KB 32

#define LAMBDA_INIT_F 0.78360576654f
#define ONE_MINUS_LI  0.21639423346f
#define SCALE_F 0.08838834764831845f  // 1/sqrt(128)
#define CMAX_F 16.0f                   // static softmax shift: P = exp(s - 16)

typedef __attribute__((ext_vector_type(8))) short bf16x8;
typedef __attribute__((ext_vector_type(4))) float f32x4;
typedef __attribute__((ext_vector_type(4))) uint32_t u32x4;
typedef __attribute__((ext_vector_type(2))) uint32_t u32x2;

// Loop LDS (bytes): Kb[2] @0,@16384; Vb[2] @32768,@49152; P[2] @65536 (2x8KB, dbuf).
// Epilogue overlay: X2[64][260] f32 @0 (66560), Ssum[2][64] @66560, LR @67072.
// SM_BYTES=81920 -> exactly 2 blocks/CU (163840 = 160KB).
#define SMB_VBASE 32768u
#define SMB_P 65536u
#define SMB_SS 66560u
#define SMB_LR 67072u
#define SM_BYTES 81920

// ws blob: per (b,hp,kt) 32 KB = [K image 16KB][V image 16KB], byte-exact LDS content
#define BLOB_BYTES 32768u

__device__ __forceinline__ unsigned short f2bf(float x) {
  union { __hip_bfloat16 h; unsigned short u; } v;
  v.h = __float2bfloat16(x);
  return v.u;
}
__device__ __forceinline__ uint32_t pk2(float a, float b) {
  return (uint32_t)f2bf(a) | ((uint32_t)f2bf(b) << 16);
}
// K image (within 16KB buffer): [att*32+row][128 d] bf16, 256B rows, XOR-swizzled
__device__ __forceinline__ uint32_t kb_byte(int att, int row, int d) {
  uint32_t o = ((uint32_t)(att * 32 + row)) * 256u + ((uint32_t)d) * 2u;
  return o ^ (((uint32_t)(row & 7)) << 4);
}
// V image (within 16KB buffer)
__device__ __forceinline__ uint32_t v_base(int col, int k) {
  uint32_t o = ((uint32_t)(col >> 2)) * 256u + ((uint32_t)(k >> 3)) * 64u +
               ((uint32_t)(col & 3)) * 16u + ((uint32_t)(k & 7)) * 2u;
  o ^= (((uint32_t)((col >> 2) & 7)) << 4);
  o ^= (((uint32_t)((col >> 2) & 1)) << 6);
  return o;
}
// P (within 8KB buffer): [att][q 0..63][k 0..31] bf16, 64B rows,
// XOR-swizzled byte ^= (qrow&6)<<3
__device__ __forceinline__ uint32_t p_off(int att, int qrow, int k) {
  uint32_t o = (((uint32_t)(att * 64 + qrow)) * 32u + (uint32_t)k) * 2u;
  return SMB_P + (o ^ (((uint32_t)(qrow & 6)) << 3));
}

// ---------------- pre-pass: pack K/V into bf16 LDS-image blobs ----------------
__global__ __launch_bounds__(256, 4)
void pack_kv(const float* __restrict__ Kg, const float* __restrict__ Vg,
             char* __restrict__ ws) {
  __shared__ float lv[32 * 264];
  const int n = blockIdx.x;          // (b*16+hp)*64 + kt
  const int kt = n & 63;
  const int bh = n >> 6;
  const int b = bh >> 4;
  const int hp = bh & 15;
  const int t = threadIdx.x;
  char* blob = ws + (size_t)n * BLOB_BYTES;

  // ---- K image ----
  {
    const int r64 = t >> 2;
    const int att = r64 >> 5, row = r64 & 31;
    const int dq = (t & 3) * 32;
    const float* src =
        Kg + (size_t)(b * S_LEN + kt * KB + row) * HD + (2 * hp + att) * 128 + dq;
    float e[32];
    #pragma unroll
    for (int m = 0; m < 8; ++m) {
      f32x4 f = *(const f32x4*)(src + 4 * m);
      e[4 * m + 0] = f[0]; e[4 * m + 1] = f[1];
      e[4 * m + 2] = f[2]; e[4 * m + 3] = f[3];
    }
    #pragma unroll
    for (int m = 0; m < 4; ++m) {
      u32x4 w;
      w.x = pk2(e[8 * m + 0], e[8 * m + 1]);
      w.y = pk2(e[8 * m + 2], e[8 * m + 3]);
      w.z = pk2(e[8 * m + 4], e[8 * m + 5]);
      w.w = pk2(e[8 * m + 6], e[8 * m + 7]);
      *(u32x4*)(blob + kb_byte(att, row, dq + 8 * m)) = w;
    }
  }
  // ---- V -> LDS f32 ----
  {
    const int r = t >> 3, s = (t & 7) * 32;
    const float* src = Vg + (size_t)(b * S_LEN + kt * KB + r) * HD + hp * 256 + s;
    #pragma unroll
    for (int m = 0; m < 8; ++m)
      *(f32x4*)(lv + r * 264 + s + 4 * m) = *(const f32x4*)(src + 4 * m);
  }
  __syncthreads();
  // ---- V image ----
  {
    const int col = t;
    #pragma unroll
    for (int k8 = 0; k8 < 4; ++k8) {
      float v0 = lv[(8 * k8 + 0) * 264 + col];
      float v1 = lv[(8 * k8 + 1) * 264 + col];
      float v2 = lv[(8 * k8 + 2) * 264 + col];
      float v3 = lv[(8 * k8 + 3) * 264 + col];
      float v4 = lv[(8 * k8 + 4) * 264 + col];
      float v5 = lv[(8 * k8 + 5) * 264 + col];
      float v6 = lv[(8 * k8 + 6) * 264 + col];
      float v7 = lv[(8 * k8 + 7) * 264 + col];
      u32x4 w;
      w.x = pk2(v0, v1); w.y = pk2(v2, v3);
      w.z = pk2(v4, v5); w.w = pk2(v6, v7);
      *(u32x4*)(blob + 16384 + v_base(col, 8 * k8)) = w;
    }
  }
}

// --- attention: QB=64, ki-split, dbuf K/V/P, issue-at-top (drain-covered), 1 barrier ---
__global__ __launch_bounds__(512, 2)
void diffattn_fwd(const float* __restrict__ Qg, const char* __restrict__ ws,
                  const float* __restrict__ lq1, const float* __restrict__ lk1,
                  const float* __restrict__ lq2, const float* __restrict__ lk2,
                  const float* __restrict__ Wg, float* __restrict__ Og) {
  __shared__ __align__(16) char sm[SM_BYTES];

  const int tid = threadIdx.x;
  const int lane = tid & 63;
  const int c = lane & 15;       // MFMA lane col index (= q-row within 16-subtile)
  const int g = lane >> 4;       // MFMA k-group
  const int wv = tid >> 6;       // 0..7
  const int att = wv >> 2;       // which attention (q1k1 / q2k2)
  const int qh = (wv >> 1) & 1;  // which 32-row half of the 64-row q block
  const int ch = wv & 1;         // V column half AND k-row half (ki) for QK

  // block swizzle: 4 (b,hp) per XCD, qt descending (heavy blocks first)
  const int n = blockIdx.x;               // 0..1023
  const int bh = (n & 7) * 4 + ((n >> 3) >> 5);
  const int qt = 31 - ((n >> 3) & 31);
  const int b = bh >> 4;
  const int hp = bh & 15;
  const int qb = qt * QB;
  const int nt = 2 * qt + 2;              // k-tiles (KB=32), nt >= 2

  const float* qg = Qg + (size_t)b * S_LEN * HD + (size_t)hp * 256 + (size_t)qb * HD;
  const char* bhb = ws + (size_t)(b * 16 + hp) * (64u * BLOB_BYTES);

  // lambda (per-wave shuffle reduce)
  float d1 = lq1[lane] * lk1[lane] + lq1[lane + 64] * lk1[lane + 64];
  float d2 = lq2[lane] * lk2[lane] + lq2[lane + 64] * lk2[lane + 64];
  #pragma unroll
  for (int m = 1; m < 64; m <<= 1) {
    d1 += __shfl_xor(d1, m, 64);
    d2 += __shfl_xor(d2, m, 64);
  }
  const float lam = __expf(d1) - __expf(d2) + LAMBDA_INIT_F;

  // ---- Q fragments direct from global (SCALE folded) ----
  bf16x8 qf[2][4];
  #pragma unroll
  for (int qi = 0; qi < 2; ++qi) {
    const float* qrow_p = qg + (size_t)(qh * 32 + qi * 16 + c) * HD + att * 128;
    #pragma unroll
    for (int kk = 0; kk < 4; ++kk) {
      f32x4 lo = *(const f32x4*)(qrow_p + 32 * kk + 8 * g);
      f32x4 hi = *(const f32x4*)(qrow_p + 32 * kk + 8 * g + 4);
      union { bf16x8 h; u32x4 u; } r;
      r.u.x = pk2(lo[0] * SCALE_F, lo[1] * SCALE_F);
      r.u.y = pk2(lo[2] * SCALE_F, lo[3] * SCALE_F);
      r.u.z = pk2(hi[0] * SCALE_F, hi[1] * SCALE_F);
      r.u.w = pk2(hi[2] * SCALE_F, hi[3] * SCALE_F);
      qf[qi][kk] = r.h;
    }
  }

  // ---- per-lane-constant LDS byte offsets (buffer-relative) ----
  uint32_t kfo[4], vbo[8];
  #pragma unroll
  for (int kk = 0; kk < 4; ++kk) kfo[kk] = kb_byte(att, 16 * ch + c, 32 * kk + 8 * g);
  #pragma unroll
  for (int cf = 0; cf < 8; ++cf) vbo[cf] = v_base(128 * ch + 16 * cf + c, 8 * g);
  const uint32_t pa0_off = p_off(att, qh * 32 + c, 8 * g);
  const uint32_t pa1_off = p_off(att, qh * 32 + 16 + c, 8 * g);
  const uint32_t pw0_off = p_off(att, qh * 32 + c, 16 * ch + 4 * g);
  const uint32_t pw1_off = p_off(att, qh * 32 + 16 + c, 16 * ch + 4 * g);
  const int lr_self = (((att * 2 + qh) * 2 + ch) << 5);
  const int lr_twin = (((att * 2 + qh) * 2 + (ch ^ 1)) << 5);

  // ---- blob staging regs ----
  u32x4 ks0, ks1, vs0, vs1;
  const uint32_t woff = 2048u * wv + 16u * lane;
  auto ISSUE_K = [&](int i) {
    const char* s0 = bhb + (size_t)i * BLOB_BYTES + woff;
    ks0 = *(const u32x4*)(s0);
    ks1 = *(const u32x4*)(s0 + 1024);
  };
  auto ISSUE_V = [&](int i) {
    const char* s0 = bhb + (size_t)i * BLOB_BYTES + 16384u + woff;
    vs0 = *(const u32x4*)(s0);
    vs1 = *(const u32x4*)(s0 + 1024);
  };
  auto WRITE_K = [&](int i) {
    char* d = sm + (((uint32_t)(i & 1)) << 14) + woff;
    *(u32x4*)(d) = ks0;
    *(u32x4*)(d + 1024) = ks1;
  };
  auto WRITE_V = [&](int i) {
    char* d = sm + SMB_VBASE + (((uint32_t)(i & 1)) << 14) + woff;
    *(u32x4*)(d) = vs0;
    *(u32x4*)(d + 1024) = vs1;
  };

  f32x4 o[2][8];
  #pragma unroll
  for (int qi = 0; qi < 2; ++qi)
    #pragma unroll
    for (int cf = 0; cf < 8; ++cf) o[qi][cf] = (f32x4){0.f, 0.f, 0.f, 0.f};
  float lrow[2] = {0.f, 0.f};   // per-lane partial sums (own k slots); reduced in epilogue

  f32x4 stA, stB;               // S^T for the tile whose softmax is pending

  // QK for tile i -> stA/stB (no max tracking)
  auto QK = [&](int i) {
    stA = (f32x4){0.f, 0.f, 0.f, 0.f};
    stB = (f32x4){0.f, 0.f, 0.f, 0.f};
    const uint32_t kb = ((uint32_t)(i & 1)) << 14;
    #pragma unroll
    for (int kk = 0; kk < 4; ++kk) {
      bf16x8 kf = *(const bf16x8*)(sm + kb + kfo[kk]);
      stA = __builtin_amdgcn_mfma_f32_16x16x32_bf16(kf, qf[0][kk], stA, 0, 0, 0);
      stB = __builtin_amdgcn_mfma_f32_16x16x32_bf16(kf, qf[1][kk], stB, 0, 0, 0);
    }
    if (i >= 2 * qt) {
      const int koff = (i - 2 * qt) * 32 + 16 * ch;
      #pragma unroll
      for (int r = 0; r < 4; ++r) {
        if (koff + 4 * g + r > qh * 32 + c) stA[r] = -1e30f;
        if (koff + 4 * g + r > qh * 32 + 16 + c) stB[r] = -1e30f;
      }
    }
  };

  // static-max softmax: P = exp(s - 16); write into P buffer parity pb
  auto SM_P = [&](uint32_t pb) {
    {
      float p0 = __expf(stA[0] - CMAX_F);
      float p1 = __expf(stA[1] - CMAX_F);
      float p2 = __expf(stA[2] - CMAX_F);
      float p3 = __expf(stA[3] - CMAX_F);
      lrow[0] += (p0 + p1) + (p2 + p3);
      u32x2 w;
      w.x = pk2(p0, p1); w.y = pk2(p2, p3);
      *(u32x2*)(sm + pw0_off + pb) = w;
    }
    {
      float p0 = __expf(stB[0] - CMAX_F);
      float p1 = __expf(stB[1] - CMAX_F);
      float p2 = __expf(stB[2] - CMAX_F);
      float p3 = __expf(stB[3] - CMAX_F);
      lrow[1] += (p0 + p1) + (p2 + p3);
      u32x2 w;
      w.x = pk2(p0, p1); w.y = pk2(p2, p3);
      *(u32x2*)(sm + pw1_off + pb) = w;
    }
  };

  // ---- prologue ----
  ISSUE_K(0); ISSUE_V(0);
  WRITE_K(0); WRITE_V(0);
  ISSUE_K(1);
  __syncthreads();                  // K(0), V(0) visible
  QK(0);                            // reads Kbuf[0]
  WRITE_K(1);                       // ks=K(1) -> Kbuf[1]
  if (2 < nt) ISSUE_K(2);           // for WRITE_K(2) at top of t=0
  ISSUE_V(1);                       // for WRITE_V(1) at top of t=0 (1 < nt always)
  SM_P(0u);                         // softmax(0) -> P[0]
  __syncthreads();                  // delta(-1): Kbuf[1], P[0] visible

  // ---- main loop: top-A writes+issues (drain-covered), A = QK(t+1)||PV(t), B = SM ----
  for (int t = 0; t < nt; ++t) {
    const bool more = (t + 1 < nt);
    // top-A: LDS writes for future tiles (target buffers free since delta(t-1))
    if (t + 2 < nt) WRITE_K(t + 2);   // ks issued one iteration ago
    if (more)       WRITE_V(t + 1);   // vs issued one iteration ago
    // issue next prefetches (regs just freed); barrier drain covered by Phase A+B
    if (t + 3 < nt) ISSUE_K(t + 3);
    if (t + 2 < nt) ISSUE_V(t + 2);

    // Phase A
    const uint32_t pbR = ((uint32_t)(t & 1)) << 13;
    bf16x8 pa0 = *(const bf16x8*)(sm + pa0_off + pbR);
    bf16x8 pa1 = *(const bf16x8*)(sm + pa1_off + pbR);
    const uint32_t vbB = SMB_VBASE + (((uint32_t)(t & 1)) << 14);
    __builtin_amdgcn_s_setprio(1);
    if (more) QK(t + 1);            // 8 MFMA (independent of PV)
    #pragma unroll
    for (int cf = 0; cf < 8; ++cf) {
      bf16x8 vf = *(const bf16x8*)(sm + vbB + vbo[cf]);
      o[0][cf] = __builtin_amdgcn_mfma_f32_16x16x32_bf16(pa0, vf, o[0][cf], 0, 0, 0);
      o[1][cf] = __builtin_amdgcn_mfma_f32_16x16x32_bf16(pa1, vf, o[1][cf], 0, 0, 0);
    }
    __builtin_amdgcn_s_setprio(0);

    // Phase B
    if (more) {
      SM_P(((uint32_t)((t + 1) & 1)) << 13);   // softmax(t+1) -> P[(t+1)&1]
      __syncthreads();              // delta(t): P(t+1), K(t+2), V(t+1) visible
    }
  }

  // ---- epilogue: reduce lrow over g, merge twin halves, fp32 combine + RMSNorm ----
  float lred[2];
  #pragma unroll
  for (int qi = 0; qi < 2; ++qi) {
    float lr = lrow[qi];
    lr += __shfl_xor(lr, 16, 64);
    lr += __shfl_xor(lr, 32, 64);
    lred[qi] = lr;
  }
  __syncthreads();                  // all waves done with loop LDS before overlay
  float* LRf = (float*)(sm + SMB_LR);
  if (g == 0) {
    LRf[lr_self + c] = lred[0];
    LRf[lr_self + 16 + c] = lred[1];
  }
  __syncthreads();
  float lv[2][4];
  #pragma unroll
  for (int qi = 0; qi < 2; ++qi) {
    float lt = lred[qi] + LRf[lr_twin + qi * 16 + c];
    float li = 1.f / lt;
    #pragma unroll
    for (int r = 0; r < 4; ++r) lv[qi][r] = __shfl(li, 4 * g + r, 64);
  }
  float* X2 = (float*)sm;                  // [64][260] f32 overlay
  float* Ssum = (float*)(sm + SMB_SS);     // [2][64] f32

  if (att == 1) {
    #pragma unroll
    for (int qi = 0; qi < 2; ++qi)
      #pragma unroll
      for (int cf = 0; cf < 8; ++cf)
        #pragma unroll
        for (int r = 0; r < 4; ++r)
          X2[(qh * 32 + qi * 16 + 4 * g + r) * 260 + 128 * ch + 16 * cf + c] =
              o[qi][cf][r] * lv[qi][r];
  }
  __syncthreads();
  if (att == 0) {
    float ss[2][4] = {{0.f, 0.f, 0.f, 0.f}, {0.f, 0.f, 0.f, 0.f}};
    #pragma unroll
    for (int qi = 0; qi < 2; ++qi)
      #pragma unroll
      for (int cf = 0; cf < 8; ++cf)
        #pragma unroll
        for (int r = 0; r < 4; ++r) {
          float xx = o[qi][cf][r] * lv[qi][r] -
                     lam * X2[(qh * 32 + qi * 16 + 4 * g + r) * 260 +
                              128 * ch + 16 * cf + c];
          o[qi][cf][r] = xx;
          ss[qi][r] += xx * xx;
        }
    #pragma unroll
    for (int m = 1; m < 16; m <<= 1)
      #pragma unroll
      for (int qi = 0; qi < 2; ++qi)
        #pragma unroll
        for (int r = 0; r < 4; ++r) ss[qi][r] += __shfl_xor(ss[qi][r], m, 64);
    if (c == 0) {
      #pragma unroll
      for (int qi = 0; qi < 2; ++qi)
        #pragma unroll
        for (int r = 0; r < 4; ++r)
          Ssum[ch * 64 + qh * 32 + qi * 16 + 4 * g + r] = ss[qi][r];
    }
  }
  __syncthreads();
  if (att == 0) {
    float rsv[2][4];
    #pragma unroll
    for (int qi = 0; qi < 2; ++qi)
      #pragma unroll
      for (int r = 0; r < 4; ++r) {
        int row = qh * 32 + qi * 16 + 4 * g + r;
        float s = Ssum[row] + Ssum[64 + row];
        rsv[qi][r] = rsqrtf(s * (1.f / 256.f) + 1e-5f) * ONE_MINUS_LI;
      }
    #pragma unroll
    for (int cf = 0; cf < 8; ++cf) {
      float w = Wg[128 * ch + 16 * cf + c];
      #pragma unroll
      for (int qi = 0; qi < 2; ++qi)
        #pragma unroll
        for (int r = 0; r < 4; ++r) {
          int row = qh * 32 + qi * 16 + 4 * g + r;
          Og[(size_t)((size_t)b * S_LEN + qb + row) * HD + hp * 256 +
             128 * ch + 16 * cf + c] = w * o[qi][cf][r] * rsv[qi][r];
        }
    }
  }
}

extern "C" void kernel_launch(void* const* d_in, const int* in_sizes, int n_in,
                              void* d_out, int out_size, void* d_ws, size_t ws_size,
                              hipStream_t stream) {
  const float* q   = (const float*)d_in[0];
  const float* k   = (const float*)d_in[1];
  const float* v   = (const float*)d_in[2];
  const float* lq1 = (const float*)d_in[3];
  const float* lk1 = (const float*)d_in[4];
  const float* lq2 = (const float*)d_in[5];
  const float* lk2 = (const float*)d_in[6];
  const float* w   = (const float*)d_in[7];
  float* out = (float*)d_out;
  char* ws = (char*)d_ws;
  hipLaunchKernelGGL(pack_kv, dim3(2048), dim3(256), 0, stream, k, v, ws);
  hipLaunchKernelGGL(diffattn_fwd, dim3(1024), dim3(512), 0, stream,
                     q, ws, lq1, lk1, lq2, lk2, w, out);
}